// Round 1
// baseline (627.253 us; speedup 1.0000x reference)
//
#include <hip/hip_runtime.h>
#include <hip/hip_bf16.h>

#define Bb 8
#define Tt 48
#define HZ 24
#define Nn 1024
#define Hh 512
#define NHEAD 8

typedef short short8 __attribute__((ext_vector_type(8)));
typedef float f32x4 __attribute__((ext_vector_type(4)));

__device__ __forceinline__ ushort f2bf(float f) {
  uint u = __builtin_bit_cast(uint, f);
  u += 0x7FFFu + ((u >> 16) & 1u);
  return (ushort)(u >> 16);
}

// ---- prep: Wv^T in bf16 -> ws ----
__global__ void wvt_kernel(const float* __restrict__ Wv, ushort* __restrict__ Wvt) {
  int e = blockIdx.x * 256 + threadIdx.x;   // 512*512 = 262144
  int hd = e >> 9, c = e & 511;
  Wvt[e] = f2bf(Wv[c * 512 + hd]);          // Wvt[hd][c] = Wv[c][hd]
}

// ---- prep: attention weights (fp32 softmax) -> bf16 padded [B][8][32][64] ----
__global__ void attn_kernel(const float* __restrict__ xt, const float* __restrict__ tt,
                            const float* __restrict__ Wq, const float* __restrict__ bq,
                            const float* __restrict__ Wk, const float* __restrict__ bk,
                            ushort* __restrict__ attnp) {
  __shared__ float qs[24][65];
  __shared__ float ks_[48][65];
  __shared__ float sc[24][49];
  int bh = blockIdx.x;                       // 64 blocks
  int b = bh >> 3, h = bh & 7;
  int t = threadIdx.x;
  for (int e = t; e < 24 * 64; e += 256) {
    int i = e >> 6, dd = e & 63;
    float s = bq[h * 64 + dd];
    const float* r = tt + (b * 24 + i) * 64;
    #pragma unroll 8
    for (int c = 0; c < 64; ++c) s += r[c] * Wq[c * 512 + h * 64 + dd];
    qs[i][dd] = s;
  }
  for (int e = t; e < 48 * 64; e += 256) {
    int j = e >> 6, dd = e & 63;
    float s = bk[h * 64 + dd];
    const float* r = xt + (b * 48 + j) * 64;
    #pragma unroll 8
    for (int c = 0; c < 64; ++c) s += r[c] * Wk[c * 512 + h * 64 + dd];
    ks_[j][dd] = s;
  }
  __syncthreads();
  for (int e = t; e < 24 * 48; e += 256) {
    int i = e / 48, j = e - i * 48;
    float s = 0.f;
    #pragma unroll 8
    for (int dd = 0; dd < 64; ++dd) s += qs[i][dd] * ks_[j][dd];
    sc[i][j] = s * 0.125f;                   // / sqrt(64)
  }
  __syncthreads();
  if (t < 32) {
    int i = t;
    ushort* orow = attnp + ((size_t)bh * 32 + i) * 64;
    if (i < 24) {
      float mx = -1e30f;
      for (int j = 0; j < 48; ++j) mx = fmaxf(mx, sc[i][j]);
      float sum = 0.f;
      for (int j = 0; j < 48; ++j) { float e = expf(sc[i][j] - mx); sc[i][j] = e; sum += e; }
      float inv = 1.f / sum;
      for (int j = 0; j < 48; ++j) orow[j] = f2bf(sc[i][j] * inv);
      for (int j = 48; j < 64; ++j) orow[j] = 0;
    } else {
      for (int j = 0; j < 64; ++j) orow[j] = 0;
    }
  }
}

// ---- main fused kernel: per (b,n): V = bf16(EH_tile)@Wv ; X = attn@V + bv ----
#define A_BASE 0         // A[48][512] bf16, XOR-swizzled  (48KB)
#define B_BASE 49152     // B tile [128][64] bf16, swizzled (16KB)
#define V_BASE 65536     // V^T [128][64] bf16, swizzled    (16KB)

__global__ __launch_bounds__(256, 2) void main_kernel(
    const float* __restrict__ EH, const ushort* __restrict__ Wvt,
    const ushort* __restrict__ attnp, const float* __restrict__ bv,
    float* __restrict__ out) {
  __shared__ __align__(128) char smem[81920];
  int bid = blockIdx.x;
  int b = bid >> 10, n = bid & 1023;
  int t = threadIdx.x;
  int lane = t & 63, w = t >> 6;

  // zero V^T region once (pad cols j=48..63 must be 0*attn-safe; attn pad is 0,
  // but stale LDS could be NaN -> 0*NaN=NaN, so hard-zero it)
  {
    uint4* vt = (uint4*)(smem + V_BASE);
    #pragma unroll
    for (int e = 0; e < 4; ++e) vt[e * 256 + t] = make_uint4(0, 0, 0, 0);
  }

  // stage A: EH[b][j][n][0..511] fp32 -> bf16 LDS (swizzle ^((j&7)<<4))
  {
    const float* ehb = EH + (((size_t)b * Tt) * Nn + n) * Hh;
    #pragma unroll 4
    for (int it = 0; it < 24; ++it) {
      int f = it * 256 + t;                  // 48 rows * 128 float4
      int j = f >> 7, c4 = f & 127;
      float4 v = *(const float4*)(ehb + (size_t)j * (Nn * Hh) + c4 * 4);
      uint2 p;
      p.x = (uint)f2bf(v.x) | ((uint)f2bf(v.y) << 16);
      p.y = (uint)f2bf(v.z) | ((uint)f2bf(v.w) << 16);
      int off = (j << 10) + (c4 << 3);
      off ^= (j & 7) << 4;
      *(uint2*)(smem + A_BASE + off) = p;
    }
  }

  for (int ch = 0; ch < 4; ++ch) {
    f32x4 acc[3][2] = {};
    const ushort* wv_ch = Wvt + (size_t)(ch * 128) * 512;
    for (int kb = 0; kb < 8; ++kb) {
      // stage B tile [128 rows(hd)][64 k] via global_load_lds w/ pre-swizzled src
      #pragma unroll
      for (int r = 0; r < 4; ++r) {
        int a = r * 4096 + t * 16;           // linear LDS byte
        int row = a >> 7;
        int inner = (a & 127) ^ ((row & 7) << 4);
        const ushort* g = wv_ch + row * 512 + kb * 64 + (inner >> 1);
        __builtin_amdgcn_global_load_lds(
            (const __attribute__((address_space(1))) void*)g,
            (__attribute__((address_space(3))) void*)(smem + B_BASE + a), 16, 0, 0);
      }
      __syncthreads();
      #pragma unroll
      for (int ki = 0; ki < 2; ++ki) {
        short8 af[3], bfr[2];
        int kc = ki * 32 + ((lane >> 4) << 3);
        #pragma unroll
        for (int m = 0; m < 3; ++m) {
          int j = m * 16 + (lane & 15);
          int off = (j << 10) + ((kb * 64 + kc) << 1);
          off ^= (j & 7) << 4;
          af[m] = *(const short8*)(smem + A_BASE + off);
        }
        #pragma unroll
        for (int nn = 0; nn < 2; ++nn) {
          int row = w * 32 + nn * 16 + (lane & 15);
          int off = (row << 7) + (kc << 1);
          off ^= (row & 7) << 4;
          bfr[nn] = *(const short8*)(smem + B_BASE + off);
        }
        #pragma unroll
        for (int m = 0; m < 3; ++m)
          #pragma unroll
          for (int nn = 0; nn < 2; ++nn)
            acc[m][nn] = __builtin_amdgcn_mfma_f32_16x16x32_bf16(af[m], bfr[nn], acc[m][nn], 0, 0, 0);
      }
      __syncthreads();
    }
    // accums -> V^T bf16 in LDS (row=hd, col=j), swizzled
    #pragma unroll
    for (int m = 0; m < 3; ++m) {
      #pragma unroll
      for (int nn = 0; nn < 2; ++nn) {
        int hd = w * 32 + nn * 16 + (lane & 15);
        int j0 = m * 16 + ((lane >> 4) << 2);
        uint2 p;
        p.x = (uint)f2bf(acc[m][nn][0]) | ((uint)f2bf(acc[m][nn][1]) << 16);
        p.y = (uint)f2bf(acc[m][nn][2]) | ((uint)f2bf(acc[m][nn][3]) << 16);
        int off = (hd << 7) + (j0 << 1);
        off ^= (hd & 7) << 4;
        *(uint2*)(smem + V_BASE + off) = p;
      }
    }
    __syncthreads();
    // stage 2: X[i,hd] = sum_j attn[h,i,j] * V[j,hd]   (MFMA, K=64 incl zero pad)
    {
      int h = 2 * ch + (w >> 1);
      f32x4 x[2][2] = {};
      #pragma unroll
      for (int ks = 0; ks < 2; ++ks) {
        short8 pa[2], vb[2];
        #pragma unroll
        for (int itl = 0; itl < 2; ++itl) {
          int i = itl * 16 + (lane & 15);
          const ushort* g = attnp + (((size_t)(b * 8 + h) * 32 + i) * 64) + ks * 32 + ((lane >> 4) << 3);
          pa[itl] = *(const short8*)g;
        }
        #pragma unroll
        for (int nn = 0; nn < 2; ++nn) {
          int hd = w * 32 + nn * 16 + (lane & 15);
          int off = (hd << 7) + ((ks * 32 + ((lane >> 4) << 3)) << 1);
          off ^= (hd & 7) << 4;
          vb[nn] = *(const short8*)(smem + V_BASE + off);
        }
        #pragma unroll
        for (int itl = 0; itl < 2; ++itl)
          #pragma unroll
          for (int nn = 0; nn < 2; ++nn)
            x[itl][nn] = __builtin_amdgcn_mfma_f32_16x16x32_bf16(pa[itl], vb[nn], x[itl][nn], 0, 0, 0);
      }
      // store X rows i<24 (+bv; softmax rows sum to 1 so bias passes through)
      #pragma unroll
      for (int itl = 0; itl < 2; ++itl) {
        int ib = itl * 16 + ((lane >> 4) << 2);
        #pragma unroll
        for (int nn = 0; nn < 2; ++nn) {
          int hd = ch * 128 + w * 32 + nn * 16 + (lane & 15);
          float bvv = bv[hd];
          #pragma unroll
          for (int r = 0; r < 4; ++r) {
            int i = ib + r;
            if (i < 24)
              out[(((size_t)b * HZ + i) * Nn + n) * Hh + hd] = x[itl][nn][r] + bvv;
          }
        }
      }
    }
  }
}

extern "C" void kernel_launch(void* const* d_in, const int* in_sizes, int n_in,
                              void* d_out, int out_size, void* d_ws, size_t ws_size,
                              hipStream_t stream) {
  (void)in_sizes; (void)n_in; (void)out_size; (void)ws_size;
  const float* EH = (const float*)d_in[0];
  const float* xt = (const float*)d_in[1];
  const float* tt = (const float*)d_in[2];
  const float* Wq = (const float*)d_in[3];
  const float* bq = (const float*)d_in[4];
  const float* Wk = (const float*)d_in[5];
  const float* bk = (const float*)d_in[6];
  const float* Wv = (const float*)d_in[7];
  const float* bv = (const float*)d_in[8];
  float* out = (float*)d_out;
  ushort* Wvt = (ushort*)d_ws;                                   // 512 KB
  ushort* attnp = (ushort*)((char*)d_ws + 512 * 1024);           // 256 KB

  wvt_kernel<<<1024, 256, 0, stream>>>(Wv, Wvt);
  attn_kernel<<<64, 256, 0, stream>>>(xt, tt, Wq, bq, Wk, bk, attnp);
  main_kernel<<<8192, 256, 0, stream>>>(EH, Wvt, attnp, bv, out);
}

// Round 2
// 540.031 us; speedup vs baseline: 1.1615x; 1.1615x over previous
//
#include <hip/hip_runtime.h>
#include <hip/hip_bf16.h>

#define Bb 8
#define Tt 48
#define HZ 24
#define Nn 1024
#define Hh 512
#define NHEAD 8

typedef short short8 __attribute__((ext_vector_type(8)));
typedef float f32x4 __attribute__((ext_vector_type(4)));

__device__ __forceinline__ ushort f2bf(float f) {
  uint u = __builtin_bit_cast(uint, f);
  u += 0x7FFFu + ((u >> 16) & 1u);
  return (ushort)(u >> 16);
}

// ---- prep: Wv^T in bf16 -> ws ----
__global__ void wvt_kernel(const float* __restrict__ Wv, ushort* __restrict__ Wvt) {
  int e = blockIdx.x * 256 + threadIdx.x;   // 512*512 = 262144
  int hd = e >> 9, c = e & 511;
  Wvt[e] = f2bf(Wv[c * 512 + hd]);          // Wvt[hd][c] = Wv[c][hd]
}

// ---- prep: attention weights (fp32 softmax) -> bf16 padded [B][8][32][64] ----
__global__ void attn_kernel(const float* __restrict__ xt, const float* __restrict__ tt,
                            const float* __restrict__ Wq, const float* __restrict__ bq,
                            const float* __restrict__ Wk, const float* __restrict__ bk,
                            ushort* __restrict__ attnp) {
  __shared__ float qs[24][65];
  __shared__ float ks_[48][65];
  __shared__ float sc[24][49];
  int bh = blockIdx.x;                       // 64 blocks
  int b = bh >> 3, h = bh & 7;
  int t = threadIdx.x;
  for (int e = t; e < 24 * 64; e += 256) {
    int i = e >> 6, dd = e & 63;
    float s = bq[h * 64 + dd];
    const float* r = tt + (b * 24 + i) * 64;
    #pragma unroll 8
    for (int c = 0; c < 64; ++c) s += r[c] * Wq[c * 512 + h * 64 + dd];
    qs[i][dd] = s;
  }
  for (int e = t; e < 48 * 64; e += 256) {
    int j = e >> 6, dd = e & 63;
    float s = bk[h * 64 + dd];
    const float* r = xt + (b * 48 + j) * 64;
    #pragma unroll 8
    for (int c = 0; c < 64; ++c) s += r[c] * Wk[c * 512 + h * 64 + dd];
    ks_[j][dd] = s;
  }
  __syncthreads();
  for (int e = t; e < 24 * 48; e += 256) {
    int i = e / 48, j = e - i * 48;
    float s = 0.f;
    #pragma unroll 8
    for (int dd = 0; dd < 64; ++dd) s += qs[i][dd] * ks_[j][dd];
    sc[i][j] = s * 0.125f;                   // / sqrt(64)
  }
  __syncthreads();
  if (t < 32) {
    int i = t;
    ushort* orow = attnp + ((size_t)bh * 32 + i) * 64;
    if (i < 24) {
      float mx = -1e30f;
      for (int j = 0; j < 48; ++j) mx = fmaxf(mx, sc[i][j]);
      float sum = 0.f;
      for (int j = 0; j < 48; ++j) { float e = expf(sc[i][j] - mx); sc[i][j] = e; sum += e; }
      float inv = 1.f / sum;
      for (int j = 0; j < 48; ++j) orow[j] = f2bf(sc[i][j] * inv);
      for (int j = 48; j < 64; ++j) orow[j] = 0;
    } else {
      for (int j = 0; j < 64; ++j) orow[j] = 0;
    }
  }
}

// ---- main fused kernel ----
// LDS: A[48][512] bf16 swizzled (48KB) + B double-buffer 2x[128][64] bf16 (32KB) = 80KB
// V^T for stage-2 borrows a dead B buffer at end of each ch.
#define A_BASE 0
#define B_BASE 49152
#define BUFSZ  16384

__device__ __forceinline__ void stage_b(char* smem, const ushort* __restrict__ Wvt,
                                        int buf, int ch, int kb, int t) {
  const ushort* wv_ch = Wvt + (size_t)(ch * 128) * 512;
  char* base = smem + B_BASE + buf * BUFSZ;
  #pragma unroll
  for (int r = 0; r < 4; ++r) {
    int a = r * 4096 + t * 16;               // linear LDS byte (wave-uniform base + lane*16)
    int row = a >> 7;
    int inner = (a & 127) ^ ((row & 7) << 4);
    const ushort* g = wv_ch + row * 512 + kb * 64 + (inner >> 1);
    __builtin_amdgcn_global_load_lds(
        (const __attribute__((address_space(1))) void*)g,
        (__attribute__((address_space(3))) void*)(base + a), 16, 0, 0);
  }
}

__global__ __launch_bounds__(256, 2) void main_kernel(
    const float* __restrict__ EH, const ushort* __restrict__ Wvt,
    const ushort* __restrict__ attnp, const float* __restrict__ bv,
    float* __restrict__ out) {
  __shared__ __align__(128) char smem[81920];
  int bid = blockIdx.x;
  int b = bid >> 10, n = bid & 1023;
  int t = threadIdx.x;
  int lane = t & 63, w = t >> 6;

  // prologue: prefetch B(ch=0,kb=0) into buf0 — overlaps the whole A-stage below
  stage_b(smem, Wvt, 0, 0, 0, t);

  // stage A: EH[b][j][n][0..511] fp32 -> bf16 LDS (swizzle ^((j&7)<<4))
  {
    const float* ehb = EH + (((size_t)b * Tt) * Nn + n) * Hh;
    #pragma unroll 4
    for (int it = 0; it < 24; ++it) {
      int f = it * 256 + t;                  // 48 rows * 128 float4
      int j = f >> 7, c4 = f & 127;
      float4 v = *(const float4*)(ehb + (size_t)j * (Nn * Hh) + c4 * 4);
      uint2 p;
      p.x = (uint)f2bf(v.x) | ((uint)f2bf(v.y) << 16);
      p.y = (uint)f2bf(v.z) | ((uint)f2bf(v.w) << 16);
      int off = (j << 10) + (c4 << 3);
      off ^= (j & 7) << 4;
      *(uint2*)(smem + A_BASE + off) = p;
    }
  }
  __syncthreads();   // A writes visible + prologue B load complete (vmcnt(0) in barrier)

  int cur = 0;
  for (int ch = 0; ch < 4; ++ch) {
    f32x4 acc[3][2] = {};
    for (int kb = 0; kb < 8; ++kb) {
      if (kb < 7) stage_b(smem, Wvt, cur ^ 1, ch, kb + 1, t);   // prefetch next K-slice
      const char* bbuf = smem + B_BASE + cur * BUFSZ;
      #pragma unroll
      for (int ki = 0; ki < 2; ++ki) {
        short8 af[3], bfr[2];
        int kc = ki * 32 + ((lane >> 4) << 3);
        #pragma unroll
        for (int m = 0; m < 3; ++m) {
          int j = m * 16 + (lane & 15);
          int off = (j << 10) + ((kb * 64 + kc) << 1);
          off ^= (j & 7) << 4;
          af[m] = *(const short8*)(smem + A_BASE + off);
        }
        #pragma unroll
        for (int nn = 0; nn < 2; ++nn) {
          int row = w * 32 + nn * 16 + (lane & 15);
          int off = (row << 7) + (kc << 1);
          off ^= (row & 7) << 4;
          bfr[nn] = *(const short8*)(bbuf + off);
        }
        #pragma unroll
        for (int m = 0; m < 3; ++m)
          #pragma unroll
          for (int nn = 0; nn < 2; ++nn)
            acc[m][nn] = __builtin_amdgcn_mfma_f32_16x16x32_bf16(af[m], bfr[nn], acc[m][nn], 0, 0, 0);
      }
      __syncthreads();   // next-slice load complete; all reads of buf[cur] done
      cur ^= 1;
    }

    // V^T into the free buffer buf[cur] (both are dead here).
    // Pad cols j=48..63 hold stale finite Wv bf16; attn pad is exact 0 -> 0*finite = 0. Safe.
    char* vbuf = smem + B_BASE + cur * BUFSZ;
    #pragma unroll
    for (int m = 0; m < 3; ++m) {
      #pragma unroll
      for (int nn = 0; nn < 2; ++nn) {
        int hd = w * 32 + nn * 16 + (lane & 15);
        int j0 = m * 16 + ((lane >> 4) << 2);
        uint2 p;
        p.x = (uint)f2bf(acc[m][nn][0]) | ((uint)f2bf(acc[m][nn][1]) << 16);
        p.y = (uint)f2bf(acc[m][nn][2]) | ((uint)f2bf(acc[m][nn][3]) << 16);
        int off = (hd << 7) + (j0 << 1);
        off ^= (hd & 7) << 4;
        *(uint2*)(vbuf + off) = p;
      }
    }
    if (ch < 3) stage_b(smem, Wvt, cur ^ 1, ch + 1, 0, t);  // prefetch next ch under stage-2
    __syncthreads();

    // stage 2: X[i,hd] = sum_j attn[h,i,j] * V[j,hd]   (MFMA, K=64 incl zero pad)
    {
      int h = 2 * ch + (w >> 1);
      f32x4 x[2][2] = {};
      #pragma unroll
      for (int ks = 0; ks < 2; ++ks) {
        short8 pa[2], vb[2];
        #pragma unroll
        for (int itl = 0; itl < 2; ++itl) {
          int i = itl * 16 + (lane & 15);
          const ushort* g = attnp + (((size_t)(b * 8 + h) * 32 + i) * 64) + ks * 32 + ((lane >> 4) << 3);
          pa[itl] = *(const short8*)g;
        }
        #pragma unroll
        for (int nn = 0; nn < 2; ++nn) {
          int hd = w * 32 + nn * 16 + (lane & 15);
          int off = (hd << 7) + ((ks * 32 + ((lane >> 4) << 3)) << 1);
          off ^= (hd & 7) << 4;
          vb[nn] = *(const short8*)(vbuf + off);
        }
        #pragma unroll
        for (int itl = 0; itl < 2; ++itl)
          #pragma unroll
          for (int nn = 0; nn < 2; ++nn)
            x[itl][nn] = __builtin_amdgcn_mfma_f32_16x16x32_bf16(pa[itl], vb[nn], x[itl][nn], 0, 0, 0);
      }
      // store X rows i<24 (+bv; softmax rows sum to 1 so bias passes through)
      #pragma unroll
      for (int itl = 0; itl < 2; ++itl) {
        int ib = itl * 16 + ((lane >> 4) << 2);
        #pragma unroll
        for (int nn = 0; nn < 2; ++nn) {
          int hd = ch * 128 + w * 32 + nn * 16 + (lane & 15);
          float bvv = bv[hd];
          #pragma unroll
          for (int r = 0; r < 4; ++r) {
            int i = ib + r;
            if (i < 24)
              out[(((size_t)b * HZ + i) * Nn + n) * Hh + hd] = x[itl][nn][r] + bvv;
          }
        }
      }
    }
    __syncthreads();   // protect vbuf until all stage-2 reads done (next ch overwrites it)
    cur ^= 1;          // next ch computes from the buffer prefetched above
  }
}

extern "C" void kernel_launch(void* const* d_in, const int* in_sizes, int n_in,
                              void* d_out, int out_size, void* d_ws, size_t ws_size,
                              hipStream_t stream) {
  (void)in_sizes; (void)n_in; (void)out_size; (void)ws_size;
  const float* EH = (const float*)d_in[0];
  const float* xt = (const float*)d_in[1];
  const float* tt = (const float*)d_in[2];
  const float* Wq = (const float*)d_in[3];
  const float* bq = (const float*)d_in[4];
  const float* Wk = (const float*)d_in[5];
  const float* bk = (const float*)d_in[6];
  const float* Wv = (const float*)d_in[7];
  const float* bv = (const float*)d_in[8];
  float* out = (float*)d_out;
  ushort* Wvt = (ushort*)d_ws;                                   // 512 KB
  ushort* attnp = (ushort*)((char*)d_ws + 512 * 1024);           // 256 KB

  wvt_kernel<<<1024, 256, 0, stream>>>(Wv, Wvt);
  attn_kernel<<<64, 256, 0, stream>>>(xt, tt, Wq, bq, Wk, bk, attnp);
  main_kernel<<<8192, 256, 0, stream>>>(EH, Wvt, attnp, bv, out);
}